// Round 7
// baseline (317.370 us; speedup 1.0000x reference)
//
#include <hip/hip_runtime.h>
#include <hip/hip_bf16.h>
#include <cstdint>
#include <cstddef>

#define TOK 8192
#define DIM 1024
#define FF  2048
#define NE  8
#define NTS 40             // 256-row tile slots: <= 32 + 8 partials
#define NBLK 32            // count_rank blocks (256 tokens each)

typedef __attribute__((ext_vector_type(8))) short short8;
typedef __attribute__((ext_vector_type(4))) float f32x4;

__device__ inline void gload_lds16(const void* g, void* l) {
  __builtin_amdgcn_global_load_lds(
      (const __attribute__((address_space(1))) unsigned int*)g,
      (__attribute__((address_space(3))) unsigned int*)l, 16, 0, 0);
}

__device__ inline unsigned short f2bf(float f) {
  unsigned int u = __float_as_uint(f);
  u += 0x7fffu + ((u >> 16) & 1u);   // RNE
  return (unsigned short)(u >> 16);
}
__device__ inline float bf2f(unsigned short u) {
  return __uint_as_float(((unsigned int)u) << 16);
}

// ---------------- weight fp32 -> bf16 ----------------
__global__ __launch_bounds__(256) void convert_kernel(
    const float* __restrict__ src, unsigned short* __restrict__ dst, int n) {
  const int stride = gridDim.x * blockDim.x * 4;
  for (int i = (blockIdx.x * blockDim.x + threadIdx.x) * 4; i < n; i += stride) {
    const float4 v = *reinterpret_cast<const float4*>(src + i);
    ushort4 o;
    o.x = f2bf(v.x); o.y = f2bf(v.y); o.z = f2bf(v.z); o.w = f2bf(v.w);
    *reinterpret_cast<ushort4*>(dst + i) = o;
  }
}

// ---------------- gating: logits, top-2 (highest index wins) -- no atomics ----------
__global__ __launch_bounds__(256) void gate_kernel(
    const float* __restrict__ x, const float* __restrict__ Wg,
    const float* __restrict__ bg, int* __restrict__ assign) {
  const int token = blockIdx.x * 4 + (threadIdx.x >> 6);
  const int lane = threadIdx.x & 63;
  if (token >= TOK) return;
  const float* xr = x + (size_t)token * DIM;
  float acc[NE];
#pragma unroll
  for (int e = 0; e < NE; ++e) acc[e] = 0.f;
#pragma unroll
  for (int i0 = 0; i0 < DIM; i0 += 256) {
    const int i = i0 + lane * 4;
    const float4 xv = *reinterpret_cast<const float4*>(xr + i);
#pragma unroll
    for (int e = 0; e < NE; ++e) {
      const float4 wv = *reinterpret_cast<const float4*>(Wg + e * DIM + i);
      acc[e] += xv.x * wv.x + xv.y * wv.y + xv.z * wv.z + xv.w * wv.w;
    }
  }
#pragma unroll
  for (int e = 0; e < NE; ++e) {
    float v = acc[e];
#pragma unroll
    for (int s = 32; s; s >>= 1) v += __shfl_xor(v, s);
    acc[e] = v + bg[e];
  }
  if (lane == 0) {
    float v1 = -INFINITY, v2 = -INFINITY; int i1 = 0, i2 = 0;
#pragma unroll
    for (int e = 0; e < NE; ++e) {
      const float v = acc[e];
      if (v > v1)      { v2 = v1; i2 = i1; v1 = v; i1 = e; }
      else if (v > v2) { v2 = v; i2 = e; }
    }
    assign[token] = (i1 > i2) ? i1 : i2;  // max(top2 indices); softmax-sum weight == 1.0
  }
}

// ---------------- ballot-based per-block counts + in-block ranks (no atomics) -------
__global__ __launch_bounds__(256) void count_rank_kernel(
    const int* __restrict__ assign, int* __restrict__ rank,
    int* __restrict__ blkcnt) {
  const int blk = blockIdx.x;
  const int tid = threadIdx.x;
  const int t = blk * 256 + tid;
  const int lane = tid & 63, wave = tid >> 6;
  const int a = assign[t];
  __shared__ int wcnt[4][NE];
  int myrank = 0;
#pragma unroll
  for (int e = 0; e < NE; ++e) {
    const unsigned long long m = __ballot(a == e);
    if (a == e) myrank = __popcll(m & ((1ull << lane) - 1ull));
    if (lane == 0) wcnt[wave][e] = __popcll(m);
  }
  __syncthreads();
  int pre = 0;
  for (int w = 0; w < wave; ++w) pre += wcnt[w][a];
  rank[t] = pre + myrank;
  if (tid < NE)
    blkcnt[blk * NE + tid] = wcnt[0][tid] + wcnt[1][tid] + wcnt[2][tid] + wcnt[3][tid];
}

// ---------------- scan: block offsets, expert offsets, 256-row tile table -----------
// ctrl: [16..24]=offsets, [25]=ntiles, [32..71]=tile_e, [128..167]=tile_m
__global__ void scan2_kernel(int* __restrict__ ctrl, const int* __restrict__ blkcnt,
                             int* __restrict__ blkoff) {
  const int tid = threadIdx.x;
  __shared__ int ecnt[NE];
  if (tid < NE) {
    int run = 0;
    for (int b = 0; b < NBLK; ++b) {
      blkoff[b * NE + tid] = run;
      run += blkcnt[b * NE + tid];
    }
    ecnt[tid] = run;
  }
  __syncthreads();
  if (tid == 0) {
    int s = 0, nt = 0;
#pragma unroll
    for (int e = 0; e < NE; ++e) {
      ctrl[16 + e] = s;
      const int cnt = ecnt[e];
      for (int m = 0; m * 256 < cnt; ++m) {
        ctrl[32 + nt] = e;
        ctrl[128 + nt] = m;
        ++nt;
      }
      s += cnt;
    }
    ctrl[24] = s;
    ctrl[25] = nt;
  }
  __syncthreads();
  if (tid < NE) {
    const int off = ctrl[16 + tid];
    for (int b = 0; b < NBLK; ++b) blkoff[b * NE + tid] += off;
  }
}

// ---------------- gather tokens into expert-contiguous bf16 rows (no atomics) -------
__global__ __launch_bounds__(256) void gather_kernel(
    const float* __restrict__ x, const int* __restrict__ assign,
    const int* __restrict__ rank, const int* __restrict__ blkoff,
    int* __restrict__ ridx, unsigned short* __restrict__ Xb) {
  const int token = blockIdx.x;
  const int a = assign[token];
  const int row = blkoff[(token >> 8) * NE + a] + rank[token];
  if (threadIdx.x == 0) ridx[row] = token;
  const int j = threadIdx.x * 4;
  const float4 v = *reinterpret_cast<const float4*>(x + (size_t)token * DIM + j);
  ushort4 o;
  o.x = f2bf(v.x); o.y = f2bf(v.y); o.z = f2bf(v.z); o.w = f2bf(v.w);
  *reinterpret_cast<ushort4*>(Xb + (size_t)row * DIM + j) = o;
}

// ================= grouped GEMM1: H = Xb @ W1e^T + b1 (bf16 out) =====================
// BM=256 BN=256 BK=64 (2 K-halves of 32), 512 thr / 8 waves (2Mx4N), dbuf LDS 128KB.
// 4 phases per K-tile; half-granular staging, counted vmcnt(4) twice per tile (T3/T4),
// setprio around MFMA clusters (T5), XOR LDS swizzle staged via pre-swizzled src (T2).
__global__ __launch_bounds__(512, 2) void gemm1_kernel(
    const unsigned short* __restrict__ Xb, const unsigned short* __restrict__ W1b,
    const float* __restrict__ b1, const int* __restrict__ ctrl,
    unsigned short* __restrict__ Hb) {
  const int bsw = blockIdx.x;
  const int lid = (bsw & 7) * (NTS) + (bsw >> 3);   // grid = 8*NTS, bijective XCD swizzle
  const int nx = lid & 7;                           // 8 n-tiles of 256 -> N=2048
  const int ti = lid >> 3;
  if (ti >= ctrl[25]) return;
  const int e = ctrl[32 + ti];
  const int m_tile = ctrl[128 + ti];
  const int base = ctrl[16 + e];
  const int count = ctrl[17 + e] - base;
  const int n0 = nx * 256;
  constexpr int K = DIM, NT = DIM / 64;
  __shared__ char smem[131072];   // [2 buf][ A: 2x16KB | B: 2x16KB ]
  const int tid = threadIdx.x, wave = tid >> 6, lane = tid & 63;
  const int wm = wave >> 2, wn = wave & 3;
  const int l15 = lane & 15;
  const int jsw = ((lane >> 4) ^ ((lane >> 1) & 3)) * 16;        // read-side swizzle (bytes)
  const int sl_r = lane >> 2;                                    // stage: row in 16-row chunk
  const int sl_k = ((lane & 3) ^ ((lane >> 3) & 3)) * 8;         // stage: pre-swizzled src k
  const unsigned short* Bg = W1b + ((size_t)e * FF + n0) * K;
  const int arow0 = base + m_tile * 256;            // FIX r6: include expert base offset
  f32x4 acc[8][4] = {};
  short8 a[8], bb[2];

  auto stA = [&](int buf, int kh, int t) {
#pragma unroll
    for (int it = 0; it < 2; ++it) {
      const int ch = it * 8 + wave;
      int r = arow0 + ch * 16 + sl_r;
      r = (r > TOK - 1) ? TOK - 1 : r;                 // clamp: no OOB reads
      gload_lds16(Xb + (size_t)r * K + t * 64 + kh * 32 + sl_k,
                  smem + buf + kh * 16384 + ch * 1024);
    }
  };
  auto stB = [&](int buf, int kh, int t) {
#pragma unroll
    for (int it = 0; it < 2; ++it) {
      const int ch = it * 8 + wave;
      const int c = ch * 16 + sl_r;
      gload_lds16(Bg + (size_t)c * K + t * 64 + kh * 32 + sl_k,
                  smem + buf + 32768 + kh * 16384 + ch * 1024);
    }
  };
  auto rdA = [&](int buf, int kh) {
#pragma unroll
    for (int i = 0; i < 8; ++i)
      a[i] = *reinterpret_cast<const short8*>(
          smem + buf + kh * 16384 + (wm * 128 + i * 16 + l15) * 64 + jsw);
  };
  auto rdB = [&](int buf, int kh, int ng) {
#pragma unroll
    for (int j = 0; j < 2; ++j)
      bb[j] = *reinterpret_cast<const short8*>(
          smem + buf + 32768 + kh * 16384 + (wn * 64 + (ng * 2 + j) * 16 + l15) * 64 + jsw);
  };
  auto mf = [&](int ng) {
    __builtin_amdgcn_s_setprio(1);
#pragma unroll
    for (int i = 0; i < 8; ++i)
#pragma unroll
      for (int j = 0; j < 2; ++j)
        acc[i][ng * 2 + j] = __builtin_amdgcn_mfma_f32_16x16x32_bf16(
            a[i], bb[j], acc[i][ng * 2 + j], 0, 0, 0);
    __builtin_amdgcn_s_setprio(0);
  };

  asm volatile("s_waitcnt vmcnt(0) lgkmcnt(0)" ::: "memory");
  stA(0, 0, 0); stB(0, 0, 0); stA(0, 1, 0); stB(0, 1, 0);   // issue order: A0 B0 A1 B1
  asm volatile("s_waitcnt vmcnt(4)" ::: "memory");          // A0,B0 ready; A1,B1 in flight
  __builtin_amdgcn_s_barrier();
  __builtin_amdgcn_sched_barrier(0);

#pragma unroll 1
  for (int t = 0; t < NT; ++t) {
    const int cur = (t & 1) << 16;
    const int nxt = cur ^ 65536;
    const int t1 = (t + 1 == NT) ? 0 : t + 1;   // last iter: dead re-stage of tile 0
    // q0: compute kh0 x n-group0   | stage A0(t+1)
    stA(nxt, 0, t1);
    rdA(cur, 0); rdB(cur, 0, 0);
    mf(0);
    __builtin_amdgcn_s_barrier(); __builtin_amdgcn_sched_barrier(0);
    // q1: compute kh0 x n-group1   | stage B0(t+1) ; retire A1,B1 of current tile
    stB(nxt, 0, t1);
    rdB(cur, 0, 1);
    mf(1);
    asm volatile("s_waitcnt vmcnt(4)" ::: "memory");
    __builtin_amdgcn_s_barrier(); __builtin_amdgcn_sched_barrier(0);
    // q2: compute kh1 x n-group0   | stage A1(t+1)
    stA(nxt, 1, t1);
    rdA(cur, 1); rdB(cur, 1, 0);
    mf(0);
    __builtin_amdgcn_s_barrier(); __builtin_amdgcn_sched_barrier(0);
    // q3: compute kh1 x n-group1   | stage B1(t+1) ; retire A0,B0 of next tile
    stB(nxt, 1, t1);
    rdB(cur, 1, 1);
    mf(1);
    asm volatile("s_waitcnt vmcnt(4)" ::: "memory");
    __builtin_amdgcn_s_barrier(); __builtin_amdgcn_sched_barrier(0);
  }

  const float* b1e = b1 + (size_t)e * FF;
  const int rb = wm * 128 + (lane >> 4) * 4;
  const int cb = n0 + wn * 64 + l15;
#pragma unroll
  for (int nf = 0; nf < 4; ++nf) {
    const int col = cb + nf * 16;
    const float bias = b1e[col];
#pragma unroll
    for (int i = 0; i < 8; ++i) {
#pragma unroll
      for (int rr = 0; rr < 4; ++rr) {
        const int lr = m_tile * 256 + rb + i * 16 + rr;
        if (lr < count)
          Hb[(size_t)(base + lr) * FF + col] = f2bf(acc[i][nf][rr] + bias);
      }
    }
  }
}

// ---------------- LayerNorm + exact GELU, in place on Hb ----------------
__global__ __launch_bounds__(256) void ln_gelu_kernel(
    unsigned short* __restrict__ Hb, const float* __restrict__ ln_g,
    const float* __restrict__ ln_b, const int* __restrict__ offsets) {
  const int row = blockIdx.x;
  int e = 0;
#pragma unroll
  for (int i = 1; i < NE; ++i) e += (row >= offsets[i]) ? 1 : 0;
  unsigned short* h = Hb + (size_t)row * FF;
  const int tid = threadIdx.x;
  const int lane = tid & 63, wave = tid >> 6;
  float v[8];
  float sum = 0.f, sq = 0.f;
  short8 raw = *reinterpret_cast<const short8*>(h + tid * 8);
#pragma unroll
  for (int i = 0; i < 8; ++i) {
    v[i] = bf2f((unsigned short)raw[i]);
    sum += v[i]; sq += v[i] * v[i];
  }
#pragma unroll
  for (int s = 32; s; s >>= 1) { sum += __shfl_xor(sum, s); sq += __shfl_xor(sq, s); }
  __shared__ float red[8];
  if (lane == 0) { red[wave] = sum; red[wave + 4] = sq; }
  __syncthreads();
  sum = red[0] + red[1] + red[2] + red[3];
  sq  = red[4] + red[5] + red[6] + red[7];
  const float mu = sum * (1.f / FF);
  const float var = sq * (1.f / FF) - mu * mu;
  const float rstd = rsqrtf(var + 1e-5f);
  const float* ge = ln_g + (size_t)e * FF + tid * 8;
  const float* be = ln_b + (size_t)e * FF + tid * 8;
  short8 outv;
#pragma unroll
  for (int i = 0; i < 8; ++i) {
    const float t = (v[i] - mu) * rstd * ge[i] + be[i];
    const float g = 0.5f * t * (1.f + erff(t * 0.70710678118f));
    outv[i] = (short)f2bf(g);
  }
  *reinterpret_cast<short8*>(h + tid * 8) = outv;
}

// ================= grouped GEMM2: out[t] = (Hb @ W2e^T + b2)*se + x[t] ===============
// BM=256 BN=128 BK=64, 512 thr / 8 waves (2Mx4N, wave=128x32), dbuf LDS 96KB.
__global__ __launch_bounds__(512, 2) void gemm2_kernel(
    const unsigned short* __restrict__ Hb, const unsigned short* __restrict__ W2b,
    const float* __restrict__ b2, const float* __restrict__ res_scale,
    const int* __restrict__ ctrl, const int* __restrict__ ridx,
    const float* __restrict__ x, float* __restrict__ out) {
  const int bsw = blockIdx.x;
  const int lid = (bsw & 7) * (NTS) + (bsw >> 3);
  const int nx = lid & 7;                           // 8 n-tiles of 128 -> N=1024
  const int ti = lid >> 3;
  if (ti >= ctrl[25]) return;
  const int e = ctrl[32 + ti];
  const int m_tile = ctrl[128 + ti];
  const int base = ctrl[16 + e];
  const int count = ctrl[17 + e] - base;
  const int n0 = nx * 128;
  constexpr int K = FF, NT = FF / 64;
  __shared__ char smem[98304];    // [2 buf][ A: 2x16KB | B: 2x8KB ] stride 49152
  const int tid = threadIdx.x, wave = tid >> 6, lane = tid & 63;
  const int wm = wave >> 2, wn = wave & 3;
  const int l15 = lane & 15;
  const int jsw = ((lane >> 4) ^ ((lane >> 1) & 3)) * 16;
  const int sl_r = lane >> 2;
  const int sl_k = ((lane & 3) ^ ((lane >> 3) & 3)) * 8;
  const unsigned short* Bg = W2b + ((size_t)e * DIM + n0) * K;
  const int arow0 = base + m_tile * 256;            // FIX r6: include expert base offset
  f32x4 acc[8][2] = {};
  short8 a[8], bb;

  auto stA = [&](int buf, int kh, int t) {
#pragma unroll
    for (int it = 0; it < 2; ++it) {
      const int ch = it * 8 + wave;
      int r = arow0 + ch * 16 + sl_r;
      r = (r > TOK - 1) ? TOK - 1 : r;
      gload_lds16(Hb + (size_t)r * K + t * 64 + kh * 32 + sl_k,
                  smem + buf + kh * 16384 + ch * 1024);
    }
  };
  auto stB = [&](int buf, int kh, int t) {
    const int ch = wave;                               // 8 chunks = 8KB half
    const int c = ch * 16 + sl_r;
    gload_lds16(Bg + (size_t)c * K + t * 64 + kh * 32 + sl_k,
                smem + buf + 32768 + kh * 8192 + ch * 1024);
  };
  auto rdA = [&](int buf, int kh) {
#pragma unroll
    for (int i = 0; i < 8; ++i)
      a[i] = *reinterpret_cast<const short8*>(
          smem + buf + kh * 16384 + (wm * 128 + i * 16 + l15) * 64 + jsw);
  };
  auto rdB = [&](int buf, int kh, int nf) {
    bb = *reinterpret_cast<const short8*>(
        smem + buf + 32768 + kh * 8192 + (wn * 32 + nf * 16 + l15) * 64 + jsw);
  };
  auto mf = [&](int nf) {
    __builtin_amdgcn_s_setprio(1);
#pragma unroll
    for (int i = 0; i < 8; ++i)
      acc[i][nf] = __builtin_amdgcn_mfma_f32_16x16x32_bf16(a[i], bb, acc[i][nf], 0, 0, 0);
    __builtin_amdgcn_s_setprio(0);
  };

  asm volatile("s_waitcnt vmcnt(0) lgkmcnt(0)" ::: "memory");
  stA(0, 0, 0); stB(0, 0, 0); stA(0, 1, 0); stB(0, 1, 0);   // A0(2) B0(1) A1(2) B1(1)
  asm volatile("s_waitcnt vmcnt(3)" ::: "memory");
  __builtin_amdgcn_s_barrier();
  __builtin_amdgcn_sched_barrier(0);

#pragma unroll 1
  for (int t = 0; t < NT; ++t) {
    const int cur = (t & 1) ? 49152 : 0;
    const int nxt = 49152 - cur;
    const int t1 = (t + 1 == NT) ? 0 : t + 1;
    // q0
    stA(nxt, 0, t1);
    rdA(cur, 0); rdB(cur, 0, 0);
    mf(0);
    __builtin_amdgcn_s_barrier(); __builtin_amdgcn_sched_barrier(0);
    // q1
    stB(nxt, 0, t1);
    rdB(cur, 0, 1);
    mf(1);
    asm volatile("s_waitcnt vmcnt(3)" ::: "memory");
    __builtin_amdgcn_s_barrier(); __builtin_amdgcn_sched_barrier(0);
    // q2
    stA(nxt, 1, t1);
    rdA(cur, 1); rdB(cur, 1, 0);
    mf(0);
    __builtin_amdgcn_s_barrier(); __builtin_amdgcn_sched_barrier(0);
    // q3
    stB(nxt, 1, t1);
    rdB(cur, 1, 1);
    mf(1);
    asm volatile("s_waitcnt vmcnt(3)" ::: "memory");
    __builtin_amdgcn_s_barrier(); __builtin_amdgcn_sched_barrier(0);
  }

  const float* b2e = b2 + (size_t)e * DIM;
  const float se = res_scale[e];
  const int rb = wm * 128 + (lane >> 4) * 4;
  const int cb = n0 + wn * 32 + l15;
#pragma unroll
  for (int i = 0; i < 8; ++i) {
#pragma unroll
    for (int rr = 0; rr < 4; ++rr) {
      const int lr = m_tile * 256 + rb + i * 16 + rr;
      if (lr < count) {
        const int trow = ridx[base + lr];
        const float* xrow = x + (size_t)trow * DIM;
        float* orow = out + (size_t)trow * DIM;
#pragma unroll
        for (int nf = 0; nf < 2; ++nf) {
          const int col = cb + nf * 16;
          orow[col] = (acc[i][nf][rr] + b2e[col]) * se + xrow[col];
        }
      }
    }
  }
}

extern "C" void kernel_launch(void* const* d_in, const int* in_sizes, int n_in,
                              void* d_out, int out_size, void* d_ws, size_t ws_size,
                              hipStream_t stream) {
  const float* x         = (const float*)d_in[0];
  const float* Wg        = (const float*)d_in[1];
  const float* bg        = (const float*)d_in[2];
  const float* W1        = (const float*)d_in[3];
  const float* b1        = (const float*)d_in[4];
  const float* ln_g      = (const float*)d_in[5];
  const float* ln_b      = (const float*)d_in[6];
  const float* W2        = (const float*)d_in[7];
  const float* b2        = (const float*)d_in[8];
  const float* res_scale = (const float*)d_in[9];
  float* out = (float*)d_out;

  char* ws = (char*)d_ws;
  unsigned short* W1b = (unsigned short*)(ws);
  unsigned short* W2b = (unsigned short*)(ws + 33554432);
  unsigned short* Xb  = (unsigned short*)(ws + 67108864);
  unsigned short* Hb  = (unsigned short*)(ws + 83886080);
  int* assign  = (int*)(ws + 117964800);
  int* ridx    = (int*)(ws + 117997568);
  int* ctrl    = (int*)(ws + 118030336);
  int* rank    = (int*)(ws + 118034432);
  int* blkcnt  = (int*)(ws + 118067200);
  int* blkoff  = (int*)(ws + 118068224);

  gate_kernel<<<TOK / 4, 256, 0, stream>>>(x, Wg, bg, assign);
  convert_kernel<<<2048, 256, 0, stream>>>(W1, W1b, NE * FF * DIM);
  convert_kernel<<<2048, 256, 0, stream>>>(W2, W2b, NE * DIM * FF);
  count_rank_kernel<<<NBLK, 256, 0, stream>>>(assign, rank, blkcnt);
  scan2_kernel<<<1, 64, 0, stream>>>(ctrl, blkcnt, blkoff);
  gather_kernel<<<TOK, 256, 0, stream>>>(x, assign, rank, blkoff, ridx, Xb);
  gemm1_kernel<<<8 * NTS, 512, 0, stream>>>(Xb, W1b, b1, ctrl, Hb);
  ln_gelu_kernel<<<TOK, 256, 0, stream>>>(Hb, ln_g, ln_b, ctrl + 16);
  gemm2_kernel<<<8 * NTS, 512, 0, stream>>>(Hb, W2b, b2, res_scale, ctrl, ridx, x, out);
}

// Round 8
// 314.722 us; speedup vs baseline: 1.0084x; 1.0084x over previous
//
#include <hip/hip_runtime.h>
#include <hip/hip_bf16.h>
#include <cstdint>
#include <cstddef>

#define TOK 8192
#define DIM 1024
#define FF  2048
#define NE  8
#define MAXTILES 72        // 128-row m-tile slots: 64 + 8 partials
#define NBLK 32            // count_rank blocks (256 tokens each)

typedef __attribute__((ext_vector_type(8))) short short8;
typedef __attribute__((ext_vector_type(4))) float f32x4;

__device__ inline void gload_lds16(const void* g, void* l) {
  __builtin_amdgcn_global_load_lds(
      (const __attribute__((address_space(1))) unsigned int*)g,
      (__attribute__((address_space(3))) unsigned int*)l, 16, 0, 0);
}

__device__ inline unsigned short f2bf(float f) {
  unsigned int u = __float_as_uint(f);
  u += 0x7fffu + ((u >> 16) & 1u);   // RNE
  return (unsigned short)(u >> 16);
}
__device__ inline float bf2f(unsigned short u) {
  return __uint_as_float(((unsigned int)u) << 16);
}

// ---------------- weight fp32 -> bf16 ----------------
__global__ __launch_bounds__(256) void convert_kernel(
    const float* __restrict__ src, unsigned short* __restrict__ dst, int n) {
  const int stride = gridDim.x * blockDim.x * 4;
  for (int i = (blockIdx.x * blockDim.x + threadIdx.x) * 4; i < n; i += stride) {
    const float4 v = *reinterpret_cast<const float4*>(src + i);
    ushort4 o;
    o.x = f2bf(v.x); o.y = f2bf(v.y); o.z = f2bf(v.z); o.w = f2bf(v.w);
    *reinterpret_cast<ushort4*>(dst + i) = o;
  }
}

// ---------------- gating: logits, top-2 (highest index wins) -- no atomics ----------
__global__ __launch_bounds__(256) void gate_kernel(
    const float* __restrict__ x, const float* __restrict__ Wg,
    const float* __restrict__ bg, int* __restrict__ assign) {
  const int token = blockIdx.x * 4 + (threadIdx.x >> 6);
  const int lane = threadIdx.x & 63;
  if (token >= TOK) return;
  const float* xr = x + (size_t)token * DIM;
  float acc[NE];
#pragma unroll
  for (int e = 0; e < NE; ++e) acc[e] = 0.f;
#pragma unroll
  for (int i0 = 0; i0 < DIM; i0 += 256) {
    const int i = i0 + lane * 4;
    const float4 xv = *reinterpret_cast<const float4*>(xr + i);
#pragma unroll
    for (int e = 0; e < NE; ++e) {
      const float4 wv = *reinterpret_cast<const float4*>(Wg + e * DIM + i);
      acc[e] += xv.x * wv.x + xv.y * wv.y + xv.z * wv.z + xv.w * wv.w;
    }
  }
#pragma unroll
  for (int e = 0; e < NE; ++e) {
    float v = acc[e];
#pragma unroll
    for (int s = 32; s; s >>= 1) v += __shfl_xor(v, s);
    acc[e] = v + bg[e];
  }
  if (lane == 0) {
    float v1 = -INFINITY, v2 = -INFINITY; int i1 = 0, i2 = 0;
#pragma unroll
    for (int e = 0; e < NE; ++e) {
      const float v = acc[e];
      if (v > v1)      { v2 = v1; i2 = i1; v1 = v; i1 = e; }
      else if (v > v2) { v2 = v; i2 = e; }
    }
    assign[token] = (i1 > i2) ? i1 : i2;  // max(top2 indices); softmax-sum weight == 1.0
  }
}

// ---------------- ballot-based per-block counts + in-block ranks (no atomics) -------
__global__ __launch_bounds__(256) void count_rank_kernel(
    const int* __restrict__ assign, int* __restrict__ rank,
    int* __restrict__ blkcnt) {
  const int blk = blockIdx.x;
  const int tid = threadIdx.x;
  const int t = blk * 256 + tid;
  const int lane = tid & 63, wave = tid >> 6;
  const int a = assign[t];
  __shared__ int wcnt[4][NE];
  int myrank = 0;
#pragma unroll
  for (int e = 0; e < NE; ++e) {
    const unsigned long long m = __ballot(a == e);
    if (a == e) myrank = __popcll(m & ((1ull << lane) - 1ull));
    if (lane == 0) wcnt[wave][e] = __popcll(m);
  }
  __syncthreads();
  int pre = 0;
  for (int w = 0; w < wave; ++w) pre += wcnt[w][a];
  rank[t] = pre + myrank;
  if (tid < NE)
    blkcnt[blk * NE + tid] = wcnt[0][tid] + wcnt[1][tid] + wcnt[2][tid] + wcnt[3][tid];
}

// ---------------- scan: block offsets, expert offsets, 128-row tile table -----------
// ctrl: [16..24]=offsets, [25]=ntiles, [32..103]=tile_e, [128..199]=tile_m
__global__ void scan2_kernel(int* __restrict__ ctrl, const int* __restrict__ blkcnt,
                             int* __restrict__ blkoff) {
  const int tid = threadIdx.x;
  __shared__ int ecnt[NE];
  if (tid < NE) {
    int run = 0;
    for (int b = 0; b < NBLK; ++b) {
      blkoff[b * NE + tid] = run;
      run += blkcnt[b * NE + tid];
    }
    ecnt[tid] = run;
  }
  __syncthreads();
  if (tid == 0) {
    int s = 0, nt = 0;
#pragma unroll
    for (int e = 0; e < NE; ++e) {
      ctrl[16 + e] = s;
      const int cnt = ecnt[e];
      for (int m = 0; m * 128 < cnt; ++m) {
        ctrl[32 + nt] = e;
        ctrl[128 + nt] = m;
        ++nt;
      }
      s += cnt;
    }
    ctrl[24] = s;
    ctrl[25] = nt;
  }
  __syncthreads();
  if (tid < NE) {
    const int off = ctrl[16 + tid];
    for (int b = 0; b < NBLK; ++b) blkoff[b * NE + tid] += off;
  }
}

// ---------------- gather tokens into expert-contiguous bf16 rows (no atomics) -------
__global__ __launch_bounds__(256) void gather_kernel(
    const float* __restrict__ x, const int* __restrict__ assign,
    const int* __restrict__ rank, const int* __restrict__ blkoff,
    int* __restrict__ ridx, unsigned short* __restrict__ Xb) {
  const int token = blockIdx.x;
  const int a = assign[token];
  const int row = blkoff[(token >> 8) * NE + a] + rank[token];
  if (threadIdx.x == 0) ridx[row] = token;
  const int j = threadIdx.x * 4;
  const float4 v = *reinterpret_cast<const float4*>(x + (size_t)token * DIM + j);
  ushort4 o;
  o.x = f2bf(v.x); o.y = f2bf(v.y); o.z = f2bf(v.z); o.w = f2bf(v.w);
  *reinterpret_cast<ushort4*>(Xb + (size_t)row * DIM + j) = o;
}

// ================= grouped GEMM1: H = Xb @ W1e^T + b1 (bf16 out) =====================
// m97 regime: BM=128 BN=128 BK=64, single-buffer 32KB LDS, 2-sync K-loop, 256 thr,
// target ~4 resident blocks/CU for TLP latency hiding. T2 swizzle (pre-swizzled src).
__global__ __launch_bounds__(256) void gemm1_kernel(
    const unsigned short* __restrict__ Xb, const unsigned short* __restrict__ W1b,
    const float* __restrict__ b1, const int* __restrict__ ctrl,
    unsigned short* __restrict__ Hb) {
  const int b = blockIdx.x;
  const int lid = (b & 7) * (16 * MAXTILES / 8) + (b >> 3);  // XCD-chunked, bijective
  const int nx = lid / MAXTILES;            // ti-fastest: same-XCD blocks share B panel
  const int ti = lid % MAXTILES;
  if (ti >= ctrl[25]) return;
  const int e = ctrl[32 + ti];
  const int m_tile = ctrl[128 + ti];
  const int base = ctrl[16 + e];
  const int count = ctrl[17 + e] - base;
  const int n0 = nx * 128;
  constexpr int K = DIM;
  __shared__ unsigned short As[128 * 64];
  __shared__ unsigned short Bs[128 * 64];
  const int tid = threadIdx.x;
  const int wave = tid >> 6, lane = tid & 63;
  const int wr = wave >> 1, wc = wave & 1;
  f32x4 acc[4][4] = {};
  const unsigned short* Ag = Xb + (size_t)(base + m_tile * 128) * K;
  const unsigned short* Bg = W1b + ((size_t)e * FF + n0) * K;
  const int arow = lane >> 3;
  const int acolS = (((lane & 7) ^ arow) * 8);   // pre-swizzled source col (T2 + rule#21)
  const int l7 = lane & 7;
  const int jb = lane >> 4;
  for (int k0 = 0; k0 < K; k0 += 64) {
    __syncthreads();
#pragma unroll
    for (int it = 0; it < 4; ++it) {
      const int c = it * 4 + wave;               // wave-uniform chunk id
      const int r = c * 8 + arow;
      gload_lds16(Ag + (size_t)r * K + k0 + acolS, &As[c * 512]);
      gload_lds16(Bg + (size_t)r * K + k0 + acolS, &Bs[c * 512]);
    }
    __syncthreads();
#pragma unroll
    for (int kk = 0; kk < 64; kk += 32) {
      short8 a[4], bb[4];
      const int js = (((kk >> 3) + jb) ^ l7) << 3;
#pragma unroll
      for (int i = 0; i < 4; ++i)
        a[i] = *reinterpret_cast<const short8*>(
            &As[(wr * 64 + i * 16 + (lane & 15)) * 64 + js]);
#pragma unroll
      for (int j = 0; j < 4; ++j)
        bb[j] = *reinterpret_cast<const short8*>(
            &Bs[(wc * 64 + j * 16 + (lane & 15)) * 64 + js]);
#pragma unroll
      for (int i = 0; i < 4; ++i)
#pragma unroll
        for (int j = 0; j < 4; ++j)
          acc[i][j] = __builtin_amdgcn_mfma_f32_16x16x32_bf16(a[i], bb[j], acc[i][j], 0, 0, 0);
    }
  }
  const float* b1e = b1 + (size_t)e * FF;
  const int rbase = m_tile * 128 + wr * 64 + (lane >> 4) * 4;
  const int cbase = n0 + wc * 64 + (lane & 15);
#pragma unroll
  for (int i = 0; i < 4; ++i) {
#pragma unroll
    for (int j = 0; j < 4; ++j) {
      const int col = cbase + j * 16;
      const float bias = b1e[col];
#pragma unroll
      for (int r = 0; r < 4; ++r) {
        const int lr = rbase + i * 16 + r;
        if (lr < count)
          Hb[(size_t)(base + lr) * FF + col] = f2bf(acc[i][j][r] + bias);
      }
    }
  }
}

// ---------------- LayerNorm + exact GELU, in place on Hb ----------------
__global__ __launch_bounds__(256) void ln_gelu_kernel(
    unsigned short* __restrict__ Hb, const float* __restrict__ ln_g,
    const float* __restrict__ ln_b, const int* __restrict__ offsets) {
  const int row = blockIdx.x;
  int e = 0;
#pragma unroll
  for (int i = 1; i < NE; ++i) e += (row >= offsets[i]) ? 1 : 0;
  unsigned short* h = Hb + (size_t)row * FF;
  const int tid = threadIdx.x;
  const int lane = tid & 63, wave = tid >> 6;
  float v[8];
  float sum = 0.f, sq = 0.f;
  short8 raw = *reinterpret_cast<const short8*>(h + tid * 8);
#pragma unroll
  for (int i = 0; i < 8; ++i) {
    v[i] = bf2f((unsigned short)raw[i]);
    sum += v[i]; sq += v[i] * v[i];
  }
#pragma unroll
  for (int s = 32; s; s >>= 1) { sum += __shfl_xor(sum, s); sq += __shfl_xor(sq, s); }
  __shared__ float red[8];
  if (lane == 0) { red[wave] = sum; red[wave + 4] = sq; }
  __syncthreads();
  sum = red[0] + red[1] + red[2] + red[3];
  sq  = red[4] + red[5] + red[6] + red[7];
  const float mu = sum * (1.f / FF);
  const float var = sq * (1.f / FF) - mu * mu;
  const float rstd = rsqrtf(var + 1e-5f);
  const float* ge = ln_g + (size_t)e * FF + tid * 8;
  const float* be = ln_b + (size_t)e * FF + tid * 8;
  short8 outv;
#pragma unroll
  for (int i = 0; i < 8; ++i) {
    const float t = (v[i] - mu) * rstd * ge[i] + be[i];
    const float g = 0.5f * t * (1.f + erff(t * 0.70710678118f));
    outv[i] = (short)f2bf(g);
  }
  *reinterpret_cast<short8*>(h + tid * 8) = outv;
}

// ================= grouped GEMM2: out[t] = (Hb @ W2e^T + b2)*se + x[t] ===============
// BM=128 BN=64 BK=64, single-buffer 24KB LDS, 2-sync K-loop, 256 thr (2Mx2N, wave 64x32)
// -> W=~1088 blocks, ~4.25 resident/CU.
__global__ __launch_bounds__(256) void gemm2_kernel(
    const unsigned short* __restrict__ Hb, const unsigned short* __restrict__ W2b,
    const float* __restrict__ b2, const float* __restrict__ res_scale,
    const int* __restrict__ ctrl, const int* __restrict__ ridx,
    const float* __restrict__ x, float* __restrict__ out) {
  const int b = blockIdx.x;
  const int lid = (b & 7) * (16 * MAXTILES / 8) + (b >> 3);
  const int nx = lid / MAXTILES;            // 16 n-tiles of 64 -> N=1024
  const int ti = lid % MAXTILES;
  if (ti >= ctrl[25]) return;
  const int e = ctrl[32 + ti];
  const int m_tile = ctrl[128 + ti];
  const int base = ctrl[16 + e];
  const int count = ctrl[17 + e] - base;
  const int n0 = nx * 64;
  constexpr int K = FF;
  __shared__ unsigned short As[128 * 64];   // 16KB
  __shared__ unsigned short Bs[64 * 64];    // 8KB
  const int tid = threadIdx.x;
  const int wave = tid >> 6, lane = tid & 63;
  const int wr = wave >> 1, wc = wave & 1;
  f32x4 acc[4][2] = {};
  const unsigned short* Ag = Hb + (size_t)(base + m_tile * 128) * K;
  const unsigned short* Bg = W2b + ((size_t)e * DIM + n0) * K;
  const int arow = lane >> 3;
  const int acolS = (((lane & 7) ^ arow) * 8);
  const int l7 = lane & 7;
  const int jb = lane >> 4;
  for (int k0 = 0; k0 < K; k0 += 64) {
    __syncthreads();
#pragma unroll
    for (int it = 0; it < 4; ++it) {          // A: 16 chunks
      const int c = it * 4 + wave;
      const int r = c * 8 + arow;
      gload_lds16(Ag + (size_t)r * K + k0 + acolS, &As[c * 512]);
    }
#pragma unroll
    for (int it = 0; it < 2; ++it) {          // B: 8 chunks
      const int c = it * 4 + wave;
      const int r = c * 8 + arow;
      gload_lds16(Bg + (size_t)r * K + k0 + acolS, &Bs[c * 512]);
    }
    __syncthreads();
#pragma unroll
    for (int kk = 0; kk < 64; kk += 32) {
      short8 a[4], bb[2];
      const int js = (((kk >> 3) + jb) ^ l7) << 3;
#pragma unroll
      for (int i = 0; i < 4; ++i)
        a[i] = *reinterpret_cast<const short8*>(
            &As[(wr * 64 + i * 16 + (lane & 15)) * 64 + js]);
#pragma unroll
      for (int j = 0; j < 2; ++j)
        bb[j] = *reinterpret_cast<const short8*>(
            &Bs[(wc * 32 + j * 16 + (lane & 15)) * 64 + js]);
#pragma unroll
      for (int i = 0; i < 4; ++i)
#pragma unroll
        for (int j = 0; j < 2; ++j)
          acc[i][j] = __builtin_amdgcn_mfma_f32_16x16x32_bf16(a[i], bb[j], acc[i][j], 0, 0, 0);
    }
  }
  const float* b2e = b2 + (size_t)e * DIM;
  const float se = res_scale[e];
  const int rbase = m_tile * 128 + wr * 64 + (lane >> 4) * 4;
  const int cbase = n0 + wc * 32 + (lane & 15);
#pragma unroll
  for (int i = 0; i < 4; ++i) {
#pragma unroll
    for (int r = 0; r < 4; ++r) {
      const int lr = rbase + i * 16 + r;
      if (lr < count) {
        const int trow = ridx[base + lr];
        const float* xrow = x + (size_t)trow * DIM;
        float* orow = out + (size_t)trow * DIM;
#pragma unroll
        for (int j = 0; j < 2; ++j) {
          const int col = cbase + j * 16;
          orow[col] = (acc[i][j][r] + b2e[col]) * se + xrow[col];
        }
      }
    }
  }
}

extern "C" void kernel_launch(void* const* d_in, const int* in_sizes, int n_in,
                              void* d_out, int out_size, void* d_ws, size_t ws_size,
                              hipStream_t stream) {
  const float* x         = (const float*)d_in[0];
  const float* Wg        = (const float*)d_in[1];
  const float* bg        = (const float*)d_in[2];
  const float* W1        = (const float*)d_in[3];
  const float* b1        = (const float*)d_in[4];
  const float* ln_g      = (const float*)d_in[5];
  const float* ln_b      = (const float*)d_in[6];
  const float* W2        = (const float*)d_in[7];
  const float* b2        = (const float*)d_in[8];
  const float* res_scale = (const float*)d_in[9];
  float* out = (float*)d_out;

  char* ws = (char*)d_ws;
  unsigned short* W1b = (unsigned short*)(ws);
  unsigned short* W2b = (unsigned short*)(ws + 33554432);
  unsigned short* Xb  = (unsigned short*)(ws + 67108864);
  unsigned short* Hb  = (unsigned short*)(ws + 83886080);
  int* assign  = (int*)(ws + 117964800);
  int* ridx    = (int*)(ws + 117997568);
  int* ctrl    = (int*)(ws + 118030336);
  int* rank    = (int*)(ws + 118034432);
  int* blkcnt  = (int*)(ws + 118067200);
  int* blkoff  = (int*)(ws + 118068224);

  gate_kernel<<<TOK / 4, 256, 0, stream>>>(x, Wg, bg, assign);
  convert_kernel<<<2048, 256, 0, stream>>>(W1, W1b, NE * FF * DIM);
  convert_kernel<<<2048, 256, 0, stream>>>(W2, W2b, NE * DIM * FF);
  count_rank_kernel<<<NBLK, 256, 0, stream>>>(assign, rank, blkcnt);
  scan2_kernel<<<1, 64, 0, stream>>>(ctrl, blkcnt, blkoff);
  gather_kernel<<<TOK, 256, 0, stream>>>(x, assign, rank, blkoff, ridx, Xb);
  gemm1_kernel<<<16 * MAXTILES, 256, 0, stream>>>(Xb, W1b, b1, ctrl, Hb);
  ln_gelu_kernel<<<TOK, 256, 0, stream>>>(Hb, ln_g, ln_b, ctrl + 16);
  gemm2_kernel<<<16 * MAXTILES, 256, 0, stream>>>(Hb, W2b, b2, res_scale, ctrl, ridx, x, out);
}

// Round 9
// 290.071 us; speedup vs baseline: 1.0941x; 1.0850x over previous
//
#include <hip/hip_runtime.h>
#include <hip/hip_bf16.h>
#include <cstdint>
#include <cstddef>

#define TOK 8192
#define DIM 1024
#define FF  2048
#define NE  8
#define MAXTILES 72        // 128-row m-tile slots (gemm1): 64 + 8 partials
#define MAXT2 136          // 64-row m-tile slots (gemm2): 128 + 8 partials
#define NBLK 32            // count_rank blocks (256 tokens each)

typedef __attribute__((ext_vector_type(8))) short short8;
typedef __attribute__((ext_vector_type(4))) float f32x4;

__device__ inline void gload_lds16(const void* g, void* l) {
  __builtin_amdgcn_global_load_lds(
      (const __attribute__((address_space(1))) unsigned int*)g,
      (__attribute__((address_space(3))) unsigned int*)l, 16, 0, 0);
}

__device__ inline unsigned short f2bf(float f) {
  unsigned int u = __float_as_uint(f);
  u += 0x7fffu + ((u >> 16) & 1u);   // RNE
  return (unsigned short)(u >> 16);
}
__device__ inline float bf2f(unsigned short u) {
  return __uint_as_float(((unsigned int)u) << 16);
}

// ---------------- weight fp32 -> bf16 ----------------
__global__ __launch_bounds__(256) void convert_kernel(
    const float* __restrict__ src, unsigned short* __restrict__ dst, int n) {
  const int stride = gridDim.x * blockDim.x * 4;
  for (int i = (blockIdx.x * blockDim.x + threadIdx.x) * 4; i < n; i += stride) {
    const float4 v = *reinterpret_cast<const float4*>(src + i);
    ushort4 o;
    o.x = f2bf(v.x); o.y = f2bf(v.y); o.z = f2bf(v.z); o.w = f2bf(v.w);
    *reinterpret_cast<ushort4*>(dst + i) = o;
  }
}

// ---------------- gating: logits, top-2 (highest index wins) -- no atomics ----------
__global__ __launch_bounds__(256) void gate_kernel(
    const float* __restrict__ x, const float* __restrict__ Wg,
    const float* __restrict__ bg, int* __restrict__ assign) {
  const int token = blockIdx.x * 4 + (threadIdx.x >> 6);
  const int lane = threadIdx.x & 63;
  if (token >= TOK) return;
  const float* xr = x + (size_t)token * DIM;
  float acc[NE];
#pragma unroll
  for (int e = 0; e < NE; ++e) acc[e] = 0.f;
#pragma unroll
  for (int i0 = 0; i0 < DIM; i0 += 256) {
    const int i = i0 + lane * 4;
    const float4 xv = *reinterpret_cast<const float4*>(xr + i);
#pragma unroll
    for (int e = 0; e < NE; ++e) {
      const float4 wv = *reinterpret_cast<const float4*>(Wg + e * DIM + i);
      acc[e] += xv.x * wv.x + xv.y * wv.y + xv.z * wv.z + xv.w * wv.w;
    }
  }
#pragma unroll
  for (int e = 0; e < NE; ++e) {
    float v = acc[e];
#pragma unroll
    for (int s = 32; s; s >>= 1) v += __shfl_xor(v, s);
    acc[e] = v + bg[e];
  }
  if (lane == 0) {
    float v1 = -INFINITY, v2 = -INFINITY; int i1 = 0, i2 = 0;
#pragma unroll
    for (int e = 0; e < NE; ++e) {
      const float v = acc[e];
      if (v > v1)      { v2 = v1; i2 = i1; v1 = v; i1 = e; }
      else if (v > v2) { v2 = v; i2 = e; }
    }
    assign[token] = (i1 > i2) ? i1 : i2;  // max(top2 indices); softmax-sum weight == 1.0
  }
}

// ---------------- ballot-based per-block counts + in-block ranks (no atomics) -------
__global__ __launch_bounds__(256) void count_rank_kernel(
    const int* __restrict__ assign, int* __restrict__ rank,
    int* __restrict__ blkcnt) {
  const int blk = blockIdx.x;
  const int tid = threadIdx.x;
  const int t = blk * 256 + tid;
  const int lane = tid & 63, wave = tid >> 6;
  const int a = assign[t];
  __shared__ int wcnt[4][NE];
  int myrank = 0;
#pragma unroll
  for (int e = 0; e < NE; ++e) {
    const unsigned long long m = __ballot(a == e);
    if (a == e) myrank = __popcll(m & ((1ull << lane) - 1ull));
    if (lane == 0) wcnt[wave][e] = __popcll(m);
  }
  __syncthreads();
  int pre = 0;
  for (int w = 0; w < wave; ++w) pre += wcnt[w][a];
  rank[t] = pre + myrank;
  if (tid < NE)
    blkcnt[blk * NE + tid] = wcnt[0][tid] + wcnt[1][tid] + wcnt[2][tid] + wcnt[3][tid];
}

// ---------------- scan: block offsets, expert offsets, two tile tables --------------
// ctrl: [16..24]=offsets, [25]=ntiles128, [26]=ntiles64,
//       [32..103]=t128_e, [128..199]=t128_m, [256..391]=t64_e, [512..647]=t64_m
__global__ void scan2_kernel(int* __restrict__ ctrl, const int* __restrict__ blkcnt,
                             int* __restrict__ blkoff) {
  const int tid = threadIdx.x;
  __shared__ int ecnt[NE];
  if (tid < NE) {
    int run = 0;
    for (int b = 0; b < NBLK; ++b) {
      blkoff[b * NE + tid] = run;
      run += blkcnt[b * NE + tid];
    }
    ecnt[tid] = run;
  }
  __syncthreads();
  if (tid == 0) {
    int s = 0, nt = 0, nt2 = 0;
#pragma unroll
    for (int e = 0; e < NE; ++e) {
      ctrl[16 + e] = s;
      const int cnt = ecnt[e];
      for (int m = 0; m * 128 < cnt; ++m) {
        ctrl[32 + nt] = e;  ctrl[128 + nt] = m;  ++nt;
      }
      for (int m = 0; m * 64 < cnt && nt2 < MAXT2; ++m) {
        ctrl[256 + nt2] = e;  ctrl[512 + nt2] = m;  ++nt2;
      }
      s += cnt;
    }
    ctrl[24] = s;
    ctrl[25] = nt;
    ctrl[26] = nt2;
  }
  __syncthreads();
  if (tid < NE) {
    const int off = ctrl[16 + tid];
    for (int b = 0; b < NBLK; ++b) blkoff[b * NE + tid] += off;
  }
}

// ---------------- gather tokens into expert-contiguous bf16 rows (no atomics) -------
__global__ __launch_bounds__(256) void gather_kernel(
    const float* __restrict__ x, const int* __restrict__ assign,
    const int* __restrict__ rank, const int* __restrict__ blkoff,
    int* __restrict__ ridx, unsigned short* __restrict__ Xb) {
  const int token = blockIdx.x;
  const int a = assign[token];
  const int row = blkoff[(token >> 8) * NE + a] + rank[token];
  if (threadIdx.x == 0) ridx[row] = token;
  const int j = threadIdx.x * 4;
  const float4 v = *reinterpret_cast<const float4*>(x + (size_t)token * DIM + j);
  ushort4 o;
  o.x = f2bf(v.x); o.y = f2bf(v.y); o.z = f2bf(v.z); o.w = f2bf(v.w);
  *reinterpret_cast<ushort4*>(Xb + (size_t)row * DIM + j) = o;
}

// ================= grouped GEMM1: H = Xb @ W1e^T + b1 (bf16 out) =====================
// m97 regime: BM=128 BN=128 BK=64, single-buffer 32KB LDS, 2-sync K-loop, 256 thr,
// ~4.25 resident blocks/CU. T2 swizzle (pre-swizzled src).
__global__ __launch_bounds__(256) void gemm1_kernel(
    const unsigned short* __restrict__ Xb, const unsigned short* __restrict__ W1b,
    const float* __restrict__ b1, const int* __restrict__ ctrl,
    unsigned short* __restrict__ Hb) {
  const int b = blockIdx.x;
  const int lid = (b & 7) * (16 * MAXTILES / 8) + (b >> 3);  // XCD-chunked, bijective
  const int nx = lid / MAXTILES;            // ti-fastest: same-XCD blocks share B panel
  const int ti = lid % MAXTILES;
  if (ti >= ctrl[25]) return;
  const int e = ctrl[32 + ti];
  const int m_tile = ctrl[128 + ti];
  const int base = ctrl[16 + e];
  const int count = ctrl[17 + e] - base;
  const int n0 = nx * 128;
  constexpr int K = DIM;
  __shared__ unsigned short As[128 * 64];
  __shared__ unsigned short Bs[128 * 64];
  const int tid = threadIdx.x;
  const int wave = tid >> 6, lane = tid & 63;
  const int wr = wave >> 1, wc = wave & 1;
  f32x4 acc[4][4] = {};
  const unsigned short* Ag = Xb + (size_t)(base + m_tile * 128) * K;
  const unsigned short* Bg = W1b + ((size_t)e * FF + n0) * K;
  const int arow = lane >> 3;
  const int acolS = (((lane & 7) ^ arow) * 8);   // pre-swizzled source col (T2 + rule#21)
  const int l7 = lane & 7;
  const int jb = lane >> 4;
  for (int k0 = 0; k0 < K; k0 += 64) {
    __syncthreads();
#pragma unroll
    for (int it = 0; it < 4; ++it) {
      const int c = it * 4 + wave;               // wave-uniform chunk id
      const int r = c * 8 + arow;
      gload_lds16(Ag + (size_t)r * K + k0 + acolS, &As[c * 512]);
      gload_lds16(Bg + (size_t)r * K + k0 + acolS, &Bs[c * 512]);
    }
    __syncthreads();
#pragma unroll
    for (int kk = 0; kk < 64; kk += 32) {
      short8 a[4], bb[4];
      const int js = (((kk >> 3) + jb) ^ l7) << 3;
#pragma unroll
      for (int i = 0; i < 4; ++i)
        a[i] = *reinterpret_cast<const short8*>(
            &As[(wr * 64 + i * 16 + (lane & 15)) * 64 + js]);
#pragma unroll
      for (int j = 0; j < 4; ++j)
        bb[j] = *reinterpret_cast<const short8*>(
            &Bs[(wc * 64 + j * 16 + (lane & 15)) * 64 + js]);
#pragma unroll
      for (int i = 0; i < 4; ++i)
#pragma unroll
        for (int j = 0; j < 4; ++j)
          acc[i][j] = __builtin_amdgcn_mfma_f32_16x16x32_bf16(a[i], bb[j], acc[i][j], 0, 0, 0);
    }
  }
  const float* b1e = b1 + (size_t)e * FF;
  const int rbase = m_tile * 128 + wr * 64 + (lane >> 4) * 4;
  const int cbase = n0 + wc * 64 + (lane & 15);
#pragma unroll
  for (int i = 0; i < 4; ++i) {
#pragma unroll
    for (int j = 0; j < 4; ++j) {
      const int col = cbase + j * 16;
      const float bias = b1e[col];
#pragma unroll
      for (int r = 0; r < 4; ++r) {
        const int lr = rbase + i * 16 + r;
        if (lr < count)
          Hb[(size_t)(base + lr) * FF + col] = f2bf(acc[i][j][r] + bias);
      }
    }
  }
}

// ---------------- LayerNorm + exact GELU, in place on Hb ----------------
__global__ __launch_bounds__(256) void ln_gelu_kernel(
    unsigned short* __restrict__ Hb, const float* __restrict__ ln_g,
    const float* __restrict__ ln_b, const int* __restrict__ offsets) {
  const int row = blockIdx.x;
  int e = 0;
#pragma unroll
  for (int i = 1; i < NE; ++i) e += (row >= offsets[i]) ? 1 : 0;
  unsigned short* h = Hb + (size_t)row * FF;
  const int tid = threadIdx.x;
  const int lane = tid & 63, wave = tid >> 6;
  float v[8];
  float sum = 0.f, sq = 0.f;
  short8 raw = *reinterpret_cast<const short8*>(h + tid * 8);
#pragma unroll
  for (int i = 0; i < 8; ++i) {
    v[i] = bf2f((unsigned short)raw[i]);
    sum += v[i]; sq += v[i] * v[i];
  }
#pragma unroll
  for (int s = 32; s; s >>= 1) { sum += __shfl_xor(sum, s); sq += __shfl_xor(sq, s); }
  __shared__ float red[8];
  if (lane == 0) { red[wave] = sum; red[wave + 4] = sq; }
  __syncthreads();
  sum = red[0] + red[1] + red[2] + red[3];
  sq  = red[4] + red[5] + red[6] + red[7];
  const float mu = sum * (1.f / FF);
  const float var = sq * (1.f / FF) - mu * mu;
  const float rstd = rsqrtf(var + 1e-5f);
  const float* ge = ln_g + (size_t)e * FF + tid * 8;
  const float* be = ln_b + (size_t)e * FF + tid * 8;
  short8 outv;
#pragma unroll
  for (int i = 0; i < 8; ++i) {
    const float t = (v[i] - mu) * rstd * ge[i] + be[i];
    const float g = 0.5f * t * (1.f + erff(t * 0.70710678118f));
    outv[i] = (short)f2bf(g);
  }
  *reinterpret_cast<short8*>(h + tid * 8) = outv;
}

// ================= grouped GEMM2: out[t] = (Hb @ W2e^T + b2)*se + x[t] ===============
// BM=64 BN=128 BK=64: 24KB single-buffer LDS, 2-sync K-loop, 256 thr (2Mx2N, wave
// 32x64). Grid 8*MAXT2=1088 -> 4.25 blocks/CU; BN=128 keeps A-refetch at 8x (L3-
// absorbable, r7-verified); per-XCD B working set 8*512KB=4MB fits L2.
__global__ __launch_bounds__(256) void gemm2_kernel(
    const unsigned short* __restrict__ Hb, const unsigned short* __restrict__ W2b,
    const float* __restrict__ b2, const float* __restrict__ res_scale,
    const int* __restrict__ ctrl, const int* __restrict__ ridx,
    const float* __restrict__ x, float* __restrict__ out) {
  const int b = blockIdx.x;
  const int lid = (b & 7) * MAXT2 + (b >> 3);   // each XCD: one nx, all m-tiles
  const int nx = lid / MAXT2;                   // 8 n-tiles of 128 -> N=1024
  const int ti = lid % MAXT2;
  if (ti >= ctrl[26]) return;
  const int e = ctrl[256 + ti];
  const int m_tile = ctrl[512 + ti];
  const int base = ctrl[16 + e];
  const int count = ctrl[17 + e] - base;
  const int n0 = nx * 128;
  constexpr int K = FF;
  __shared__ unsigned short As[64 * 64];    // 8KB
  __shared__ unsigned short Bs[128 * 64];   // 16KB
  const int tid = threadIdx.x;
  const int wave = tid >> 6, lane = tid & 63;
  const int wr = wave >> 1, wc = wave & 1;
  f32x4 acc[2][4] = {};
  const unsigned short* Ag = Hb + (size_t)(base + m_tile * 64) * K;
  const unsigned short* Bg = W2b + ((size_t)e * DIM + n0) * K;
  const int arow = lane >> 3;
  const int acolS = (((lane & 7) ^ arow) * 8);
  const int l7 = lane & 7;
  const int jb = lane >> 4;
  for (int k0 = 0; k0 < K; k0 += 64) {
    __syncthreads();
#pragma unroll
    for (int it = 0; it < 2; ++it) {          // A: 8 chunks (64 rows)
      const int c = it * 4 + wave;
      const int r = c * 8 + arow;
      gload_lds16(Ag + (size_t)r * K + k0 + acolS, &As[c * 512]);
    }
#pragma unroll
    for (int it = 0; it < 4; ++it) {          // B: 16 chunks (128 rows)
      const int c = it * 4 + wave;
      const int r = c * 8 + arow;
      gload_lds16(Bg + (size_t)r * K + k0 + acolS, &Bs[c * 512]);
    }
    __syncthreads();
#pragma unroll
    for (int kk = 0; kk < 64; kk += 32) {
      short8 a[2], bb[4];
      const int js = (((kk >> 3) + jb) ^ l7) << 3;
#pragma unroll
      for (int i = 0; i < 2; ++i)
        a[i] = *reinterpret_cast<const short8*>(
            &As[(wr * 32 + i * 16 + (lane & 15)) * 64 + js]);
#pragma unroll
      for (int j = 0; j < 4; ++j)
        bb[j] = *reinterpret_cast<const short8*>(
            &Bs[(wc * 64 + j * 16 + (lane & 15)) * 64 + js]);
#pragma unroll
      for (int i = 0; i < 2; ++i)
#pragma unroll
        for (int j = 0; j < 4; ++j)
          acc[i][j] = __builtin_amdgcn_mfma_f32_16x16x32_bf16(a[i], bb[j], acc[i][j], 0, 0, 0);
    }
  }
  const float* b2e = b2 + (size_t)e * DIM;
  const float se = res_scale[e];
  const int rbase = m_tile * 64 + wr * 32 + (lane >> 4) * 4;
  const int cbase = n0 + wc * 64 + (lane & 15);
#pragma unroll
  for (int i = 0; i < 2; ++i) {
#pragma unroll
    for (int r = 0; r < 4; ++r) {
      const int lr = rbase + i * 16 + r;
      if (lr < count) {
        const int trow = ridx[base + lr];
        const float* xrow = x + (size_t)trow * DIM;
        float* orow = out + (size_t)trow * DIM;
#pragma unroll
        for (int j = 0; j < 4; ++j) {
          const int col = cbase + j * 16;
          orow[col] = (acc[i][j][r] + b2e[col]) * se + xrow[col];
        }
      }
    }
  }
}

extern "C" void kernel_launch(void* const* d_in, const int* in_sizes, int n_in,
                              void* d_out, int out_size, void* d_ws, size_t ws_size,
                              hipStream_t stream) {
  const float* x         = (const float*)d_in[0];
  const float* Wg        = (const float*)d_in[1];
  const float* bg        = (const float*)d_in[2];
  const float* W1        = (const float*)d_in[3];
  const float* b1        = (const float*)d_in[4];
  const float* ln_g      = (const float*)d_in[5];
  const float* ln_b      = (const float*)d_in[6];
  const float* W2        = (const float*)d_in[7];
  const float* b2        = (const float*)d_in[8];
  const float* res_scale = (const float*)d_in[9];
  float* out = (float*)d_out;

  char* ws = (char*)d_ws;
  unsigned short* W1b = (unsigned short*)(ws);
  unsigned short* W2b = (unsigned short*)(ws + 33554432);
  unsigned short* Xb  = (unsigned short*)(ws + 67108864);
  unsigned short* Hb  = (unsigned short*)(ws + 83886080);
  int* assign  = (int*)(ws + 117964800);
  int* ridx    = (int*)(ws + 117997568);
  int* ctrl    = (int*)(ws + 118030336);
  int* rank    = (int*)(ws + 118034432);
  int* blkcnt  = (int*)(ws + 118067200);
  int* blkoff  = (int*)(ws + 118068224);

  gate_kernel<<<TOK / 4, 256, 0, stream>>>(x, Wg, bg, assign);
  convert_kernel<<<2048, 256, 0, stream>>>(W1, W1b, NE * FF * DIM);
  convert_kernel<<<2048, 256, 0, stream>>>(W2, W2b, NE * DIM * FF);
  count_rank_kernel<<<NBLK, 256, 0, stream>>>(assign, rank, blkcnt);
  scan2_kernel<<<1, 64, 0, stream>>>(ctrl, blkcnt, blkoff);
  gather_kernel<<<TOK, 256, 0, stream>>>(x, assign, rank, blkoff, ridx, Xb);
  gemm1_kernel<<<16 * MAXTILES, 256, 0, stream>>>(Xb, W1b, b1, ctrl, Hb);
  ln_gelu_kernel<<<TOK, 256, 0, stream>>>(Hb, ln_g, ln_b, ctrl + 16);
  gemm2_kernel<<<8 * MAXT2, 256, 0, stream>>>(Hb, W2b, b2, res_scale, ctrl, ridx, x, out);
}

// Round 10
// 286.150 us; speedup vs baseline: 1.1091x; 1.0137x over previous
//
#include <hip/hip_runtime.h>
#include <hip/hip_bf16.h>
#include <cstdint>
#include <cstddef>

#define TOK 8192
#define DIM 1024
#define FF  2048
#define NE  8
#define NSLOT 48           // 256-row m-tile slots (max needed: 32+7 partials = 39)
#define NBLK 32            // count_rank blocks (256 tokens each)

typedef __attribute__((ext_vector_type(8))) short short8;
typedef __attribute__((ext_vector_type(4))) float f32x4;

__device__ inline void gload_lds16(const void* g, void* l) {
  __builtin_amdgcn_global_load_lds(
      (const __attribute__((address_space(1))) unsigned int*)g,
      (__attribute__((address_space(3))) unsigned int*)l, 16, 0, 0);
}

__device__ inline unsigned short f2bf(float f) {
  unsigned int u = __float_as_uint(f);
  u += 0x7fffu + ((u >> 16) & 1u);   // RNE
  return (unsigned short)(u >> 16);
}
__device__ inline float bf2f(unsigned short u) {
  return __uint_as_float(((unsigned int)u) << 16);
}

// ---------------- weight fp32 -> bf16 ----------------
__global__ __launch_bounds__(256) void convert_kernel(
    const float* __restrict__ src, unsigned short* __restrict__ dst, int n) {
  const int stride = gridDim.x * blockDim.x * 4;
  for (int i = (blockIdx.x * blockDim.x + threadIdx.x) * 4; i < n; i += stride) {
    const float4 v = *reinterpret_cast<const float4*>(src + i);
    ushort4 o;
    o.x = f2bf(v.x); o.y = f2bf(v.y); o.z = f2bf(v.z); o.w = f2bf(v.w);
    *reinterpret_cast<ushort4*>(dst + i) = o;
  }
}

// ---------------- gating: logits, top-2 (highest index wins) -- no atomics ----------
__global__ __launch_bounds__(256) void gate_kernel(
    const float* __restrict__ x, const float* __restrict__ Wg,
    const float* __restrict__ bg, int* __restrict__ assign) {
  const int token = blockIdx.x * 4 + (threadIdx.x >> 6);
  const int lane = threadIdx.x & 63;
  if (token >= TOK) return;
  const float* xr = x + (size_t)token * DIM;
  float acc[NE];
#pragma unroll
  for (int e = 0; e < NE; ++e) acc[e] = 0.f;
#pragma unroll
  for (int i0 = 0; i0 < DIM; i0 += 256) {
    const int i = i0 + lane * 4;
    const float4 xv = *reinterpret_cast<const float4*>(xr + i);
#pragma unroll
    for (int e = 0; e < NE; ++e) {
      const float4 wv = *reinterpret_cast<const float4*>(Wg + e * DIM + i);
      acc[e] += xv.x * wv.x + xv.y * wv.y + xv.z * wv.z + xv.w * wv.w;
    }
  }
#pragma unroll
  for (int e = 0; e < NE; ++e) {
    float v = acc[e];
#pragma unroll
    for (int s = 32; s; s >>= 1) v += __shfl_xor(v, s);
    acc[e] = v + bg[e];
  }
  if (lane == 0) {
    float v1 = -INFINITY, v2 = -INFINITY; int i1 = 0, i2 = 0;
#pragma unroll
    for (int e = 0; e < NE; ++e) {
      const float v = acc[e];
      if (v > v1)      { v2 = v1; i2 = i1; v1 = v; i1 = e; }
      else if (v > v2) { v2 = v; i2 = e; }
    }
    assign[token] = (i1 > i2) ? i1 : i2;  // max(top2 indices); softmax-sum weight == 1.0
  }
}

// ---------------- ballot-based per-block counts + in-block ranks (no atomics) -------
__global__ __launch_bounds__(256) void count_rank_kernel(
    const int* __restrict__ assign, int* __restrict__ rank,
    int* __restrict__ blkcnt) {
  const int blk = blockIdx.x;
  const int tid = threadIdx.x;
  const int t = blk * 256 + tid;
  const int lane = tid & 63, wave = tid >> 6;
  const int a = assign[t];
  __shared__ int wcnt[4][NE];
  int myrank = 0;
#pragma unroll
  for (int e = 0; e < NE; ++e) {
    const unsigned long long m = __ballot(a == e);
    if (a == e) myrank = __popcll(m & ((1ull << lane) - 1ull));
    if (lane == 0) wcnt[wave][e] = __popcll(m);
  }
  __syncthreads();
  int pre = 0;
  for (int w = 0; w < wave; ++w) pre += wcnt[w][a];
  rank[t] = pre + myrank;
  if (tid < NE)
    blkcnt[blk * NE + tid] = wcnt[0][tid] + wcnt[1][tid] + wcnt[2][tid] + wcnt[3][tid];
}

// ---------------- scan: block offsets, expert offsets, 256-row tile table -----------
// ctrl: [16..24]=offsets, [25]=ntiles, [32..79]=tile_e, [96..143]=tile_m
__global__ void scan2_kernel(int* __restrict__ ctrl, const int* __restrict__ blkcnt,
                             int* __restrict__ blkoff) {
  const int tid = threadIdx.x;
  __shared__ int ecnt[NE];
  if (tid < NE) {
    int run = 0;
    for (int b = 0; b < NBLK; ++b) {
      blkoff[b * NE + tid] = run;
      run += blkcnt[b * NE + tid];
    }
    ecnt[tid] = run;
  }
  __syncthreads();
  if (tid == 0) {
    int s = 0, nt = 0;
#pragma unroll
    for (int e = 0; e < NE; ++e) {
      ctrl[16 + e] = s;
      const int cnt = ecnt[e];
      for (int m = 0; m * 256 < cnt && nt < NSLOT; ++m) {
        ctrl[32 + nt] = e;  ctrl[96 + nt] = m;  ++nt;
      }
      s += cnt;
    }
    ctrl[24] = s;
    ctrl[25] = nt;
  }
  __syncthreads();
  if (tid < NE) {
    const int off = ctrl[16 + tid];
    for (int b = 0; b < NBLK; ++b) blkoff[b * NE + tid] += off;
  }
}

// ---------------- gather tokens into expert-contiguous bf16 rows (no atomics) -------
__global__ __launch_bounds__(256) void gather_kernel(
    const float* __restrict__ x, const int* __restrict__ assign,
    const int* __restrict__ rank, const int* __restrict__ blkoff,
    int* __restrict__ ridx, unsigned short* __restrict__ Xb) {
  const int token = blockIdx.x;
  const int a = assign[token];
  const int row = blkoff[(token >> 8) * NE + a] + rank[token];
  if (threadIdx.x == 0) ridx[row] = token;
  const int j = threadIdx.x * 4;
  const float4 v = *reinterpret_cast<const float4*>(x + (size_t)token * DIM + j);
  ushort4 o;
  o.x = f2bf(v.x); o.y = f2bf(v.y); o.z = f2bf(v.z); o.w = f2bf(v.w);
  *reinterpret_cast<ushort4*>(Xb + (size_t)row * DIM + j) = o;
}

// ================= grouped GEMM1: H = Xb @ W1e^T + b1 (bf16 out) =====================
// 256x256xBK64, 512 thr (8 waves 2Mx4N, wave tile 128x64), dbuf 128KB LDS.
// 4 phases/K-tile: {stA | a(kh0,mh0)+b(kh0) mfma} {stB | a(kh0,mh1) mfma}
// {a(kh1,mh0)+b(kh1) mfma} {a(kh1,mh1) mfma; vmcnt(0); barrier} -- staged loads get
// 2.5-3.5 phases of latency cover; vmcnt precedes the barrier so per-wave retirement
// is globally published before any cross-wave read (r7's missing piece).
__global__ __launch_bounds__(512, 2) void gemm1_kernel(
    const unsigned short* __restrict__ Xb, const unsigned short* __restrict__ W1b,
    const float* __restrict__ b1, const int* __restrict__ ctrl,
    unsigned short* __restrict__ Hb) {
  const int nx = blockIdx.x & 7;            // XCD id == n-tile -> B panel L2-resident
  const int ti = blockIdx.x >> 3;
  if (ti >= ctrl[25]) return;
  const int e = ctrl[32 + ti];
  const int m_tile = ctrl[96 + ti];
  const int base = ctrl[16 + e];
  const int count = ctrl[17 + e] - base;
  const int n0 = nx * 256;
  constexpr int K = DIM, NT = DIM / 64;
  __shared__ unsigned short Sb[2][32768];   // [buf][A 16K shorts | B 16K shorts]
  const int tid = threadIdx.x, wave = tid >> 6, lane = tid & 63;
  const int wm = wave >> 2, wn = wave & 3;
  const int l15 = lane & 15, l7 = lane & 7, jb = lane >> 4, arow = lane >> 3;
  const int acolS = (l7 ^ arow) * 8;        // pre-swizzled source col (T2 + rule#21)
  const unsigned short* Ag = Xb + (size_t)(base + m_tile * 256) * K;
  const unsigned short* Bg = W1b + ((size_t)e * FF + n0) * K;
  const int maxr = (TOK - 1) - (base + m_tile * 256);  // local row clamp
  f32x4 acc[8][4] = {};
  short8 a[4], bb[4];

  auto stA = [&](int buf, int t) {
#pragma unroll
    for (int it = 0; it < 4; ++it) {
      const int c = it * 8 + wave;
      int r = c * 8 + arow; if (r > maxr) r = maxr;
      gload_lds16(Ag + (size_t)r * K + t * 64 + acolS, &Sb[buf][c * 512]);
    }
  };
  auto stB = [&](int buf, int t) {
#pragma unroll
    for (int it = 0; it < 4; ++it) {
      const int c = it * 8 + wave;
      gload_lds16(Bg + (size_t)(c * 8 + arow) * K + t * 64 + acolS,
                  &Sb[buf][16384 + c * 512]);
    }
  };
  auto rdA = [&](int cs, int kh, int mh) {
#pragma unroll
    for (int i = 0; i < 4; ++i)
      a[i] = *reinterpret_cast<const short8*>(
          &Sb[cs][(wm * 128 + mh * 64 + i * 16 + l15) * 64 + (((kh * 4 + jb) ^ l7) << 3)]);
  };
  auto rdB = [&](int cs, int kh) {
#pragma unroll
    for (int j = 0; j < 4; ++j)
      bb[j] = *reinterpret_cast<const short8*>(
          &Sb[cs][16384 + (wn * 64 + j * 16 + l15) * 64 + (((kh * 4 + jb) ^ l7) << 3)]);
  };
  auto mf = [&](int mh) {
    __builtin_amdgcn_s_setprio(1);
#pragma unroll
    for (int i = 0; i < 4; ++i)
#pragma unroll
      for (int j = 0; j < 4; ++j)
        acc[mh * 4 + i][j] = __builtin_amdgcn_mfma_f32_16x16x32_bf16(
            a[i], bb[j], acc[mh * 4 + i][j], 0, 0, 0);
    __builtin_amdgcn_s_setprio(0);
  };

  stA(0, 0); stB(0, 0);
  asm volatile("s_waitcnt vmcnt(0)" ::: "memory");
  __builtin_amdgcn_s_barrier();

#pragma unroll 1
  for (int t = 0; t < NT; ++t) {
    const int cur = t & 1, nxt = cur ^ 1;
    const int t1 = (t + 1 == NT) ? 0 : t + 1;  // last iter: dead re-stage (drained by epilogue waits)
    // p0: stage A(t+1) in flight under 3.5 phases of compute
    stA(nxt, t1);
    rdA(cur, 0, 0); rdB(cur, 0);
    mf(0);
    __builtin_amdgcn_s_barrier();
    // p1: stage B(t+1); reuse b-frags (same kh)
    stB(nxt, t1);
    rdA(cur, 0, 1);
    mf(1);
    __builtin_amdgcn_s_barrier();
    // p2
    rdA(cur, 1, 0); rdB(cur, 1);
    mf(0);
    __builtin_amdgcn_s_barrier();
    // p3: drain own stages, then publish via barrier
    rdA(cur, 1, 1);
    mf(1);
    asm volatile("s_waitcnt vmcnt(0)" ::: "memory");
    __builtin_amdgcn_s_barrier();
  }

  const float* b1e = b1 + (size_t)e * FF;
  const int rb0 = m_tile * 256 + wm * 128 + (lane >> 4) * 4;
  const int cb = n0 + wn * 64 + l15;
#pragma unroll
  for (int f = 0; f < 8; ++f) {
    const int rbase = rb0 + (f >> 2) * 64 + (f & 3) * 16;
#pragma unroll
    for (int j = 0; j < 4; ++j) {
      const int col = cb + j * 16;
      const float bias = b1e[col];
#pragma unroll
      for (int rr = 0; rr < 4; ++rr) {
        const int lr = rbase + rr;
        if (lr < count)
          Hb[(size_t)(base + lr) * FF + col] = f2bf(acc[f][j][rr] + bias);
      }
    }
  }
}

// ---------------- LayerNorm + exact GELU, in place on Hb ----------------
__global__ __launch_bounds__(256) void ln_gelu_kernel(
    unsigned short* __restrict__ Hb, const float* __restrict__ ln_g,
    const float* __restrict__ ln_b, const int* __restrict__ offsets) {
  const int row = blockIdx.x;
  int e = 0;
#pragma unroll
  for (int i = 1; i < NE; ++i) e += (row >= offsets[i]) ? 1 : 0;
  unsigned short* h = Hb + (size_t)row * FF;
  const int tid = threadIdx.x;
  const int lane = tid & 63, wave = tid >> 6;
  float v[8];
  float sum = 0.f, sq = 0.f;
  short8 raw = *reinterpret_cast<const short8*>(h + tid * 8);
#pragma unroll
  for (int i = 0; i < 8; ++i) {
    v[i] = bf2f((unsigned short)raw[i]);
    sum += v[i]; sq += v[i] * v[i];
  }
#pragma unroll
  for (int s = 32; s; s >>= 1) { sum += __shfl_xor(sum, s); sq += __shfl_xor(sq, s); }
  __shared__ float red[8];
  if (lane == 0) { red[wave] = sum; red[wave + 4] = sq; }
  __syncthreads();
  sum = red[0] + red[1] + red[2] + red[3];
  sq  = red[4] + red[5] + red[6] + red[7];
  const float mu = sum * (1.f / FF);
  const float var = sq * (1.f / FF) - mu * mu;
  const float rstd = rsqrtf(var + 1e-5f);
  const float* ge = ln_g + (size_t)e * FF + tid * 8;
  const float* be = ln_b + (size_t)e * FF + tid * 8;
  short8 outv;
#pragma unroll
  for (int i = 0; i < 8; ++i) {
    const float t = (v[i] - mu) * rstd * ge[i] + be[i];
    const float g = 0.5f * t * (1.f + erff(t * 0.70710678118f));
    outv[i] = (short)f2bf(g);
  }
  *reinterpret_cast<short8*>(h + tid * 8) = outv;
}

// ================= grouped GEMM2: out[t] = (Hb @ W2e^T + b2)*se + x[t] ===============
// Same 4-phase structure; K=2048 (32 K-tiles), N=1024 -> 4 n-tiles, grid 192.
__global__ __launch_bounds__(512, 2) void gemm2_kernel(
    const unsigned short* __restrict__ Hb, const unsigned short* __restrict__ W2b,
    const float* __restrict__ b2, const float* __restrict__ res_scale,
    const int* __restrict__ ctrl, const int* __restrict__ ridx,
    const float* __restrict__ x, float* __restrict__ out) {
  const int b = blockIdx.x;
  const int lid = (b & 7) * 24 + (b >> 3);  // grid 192; 2 XCDs per n-tile
  const int nx = lid / NSLOT;
  const int ti = lid % NSLOT;
  if (ti >= ctrl[25]) return;
  const int e = ctrl[32 + ti];
  const int m_tile = ctrl[96 + ti];
  const int base = ctrl[16 + e];
  const int count = ctrl[17 + e] - base;
  const int n0 = nx * 256;
  constexpr int K = FF, NT = FF / 64;
  __shared__ unsigned short Sb[2][32768];
  const int tid = threadIdx.x, wave = tid >> 6, lane = tid & 63;
  const int wm = wave >> 2, wn = wave & 3;
  const int l15 = lane & 15, l7 = lane & 7, jb = lane >> 4, arow = lane >> 3;
  const int acolS = (l7 ^ arow) * 8;
  const unsigned short* Ag = Hb + (size_t)(base + m_tile * 256) * K;
  const unsigned short* Bg = W2b + ((size_t)e * DIM + n0) * K;
  const int maxr = (TOK - 1) - (base + m_tile * 256);
  f32x4 acc[8][4] = {};
  short8 a[4], bb[4];

  auto stA = [&](int buf, int t) {
#pragma unroll
    for (int it = 0; it < 4; ++it) {
      const int c = it * 8 + wave;
      int r = c * 8 + arow; if (r > maxr) r = maxr;
      gload_lds16(Ag + (size_t)r * K + t * 64 + acolS, &Sb[buf][c * 512]);
    }
  };
  auto stB = [&](int buf, int t) {
#pragma unroll
    for (int it = 0; it < 4; ++it) {
      const int c = it * 8 + wave;
      gload_lds16(Bg + (size_t)(c * 8 + arow) * K + t * 64 + acolS,
                  &Sb[buf][16384 + c * 512]);
    }
  };
  auto rdA = [&](int cs, int kh, int mh) {
#pragma unroll
    for (int i = 0; i < 4; ++i)
      a[i] = *reinterpret_cast<const short8*>(
          &Sb[cs][(wm * 128 + mh * 64 + i * 16 + l15) * 64 + (((kh * 4 + jb) ^ l7) << 3)]);
  };
  auto rdB = [&](int cs, int kh) {
#pragma unroll
    for (int j = 0; j < 4; ++j)
      bb[j] = *reinterpret_cast<const short8*>(
          &Sb[cs][16384 + (wn * 64 + j * 16 + l15) * 64 + (((kh * 4 + jb) ^ l7) << 3)]);
  };
  auto mf = [&](int mh) {
    __builtin_amdgcn_s_setprio(1);
#pragma unroll
    for (int i = 0; i < 4; ++i)
#pragma unroll
      for (int j = 0; j < 4; ++j)
        acc[mh * 4 + i][j] = __builtin_amdgcn_mfma_f32_16x16x32_bf16(
            a[i], bb[j], acc[mh * 4 + i][j], 0, 0, 0);
    __builtin_amdgcn_s_setprio(0);
  };

  stA(0, 0); stB(0, 0);
  asm volatile("s_waitcnt vmcnt(0)" ::: "memory");
  __builtin_amdgcn_s_barrier();

#pragma unroll 1
  for (int t = 0; t < NT; ++t) {
    const int cur = t & 1, nxt = cur ^ 1;
    const int t1 = (t + 1 == NT) ? 0 : t + 1;
    stA(nxt, t1);
    rdA(cur, 0, 0); rdB(cur, 0);
    mf(0);
    __builtin_amdgcn_s_barrier();
    stB(nxt, t1);
    rdA(cur, 0, 1);
    mf(1);
    __builtin_amdgcn_s_barrier();
    rdA(cur, 1, 0); rdB(cur, 1);
    mf(0);
    __builtin_amdgcn_s_barrier();
    rdA(cur, 1, 1);
    mf(1);
    asm volatile("s_waitcnt vmcnt(0)" ::: "memory");
    __builtin_amdgcn_s_barrier();
  }

  const float* b2e = b2 + (size_t)e * DIM;
  const float se = res_scale[e];
  const int rb0 = m_tile * 256 + wm * 128 + (lane >> 4) * 4;
  const int cb = n0 + wn * 64 + l15;
#pragma unroll
  for (int f = 0; f < 8; ++f) {
    const int rbase = rb0 + (f >> 2) * 64 + (f & 3) * 16;
#pragma unroll
    for (int rr = 0; rr < 4; ++rr) {
      const int lr = rbase + rr;
      if (lr < count) {
        const int trow = ridx[base + lr];
        const float* xrow = x + (size_t)trow * DIM;
        float* orow = out + (size_t)trow * DIM;
#pragma unroll
        for (int j = 0; j < 4; ++j) {
          const int col = cb + j * 16;
          orow[col] = (acc[f][j][rr] + b2e[col]) * se + xrow[col];
        }
      }
    }
  }
}

extern "C" void kernel_launch(void* const* d_in, const int* in_sizes, int n_in,
                              void* d_out, int out_size, void* d_ws, size_t ws_size,
                              hipStream_t stream) {
  const float* x         = (const float*)d_in[0];
  const float* Wg        = (const float*)d_in[1];
  const float* bg        = (const float*)d_in[2];
  const float* W1        = (const float*)d_in[3];
  const float* b1        = (const float*)d_in[4];
  const float* ln_g      = (const float*)d_in[5];
  const float* ln_b      = (const float*)d_in[6];
  const float* W2        = (const float*)d_in[7];
  const float* b2        = (const float*)d_in[8];
  const float* res_scale = (const float*)d_in[9];
  float* out = (float*)d_out;

  char* ws = (char*)d_ws;
  unsigned short* W1b = (unsigned short*)(ws);
  unsigned short* W2b = (unsigned short*)(ws + 33554432);
  unsigned short* Xb  = (unsigned short*)(ws + 67108864);
  unsigned short* Hb  = (unsigned short*)(ws + 83886080);
  int* assign  = (int*)(ws + 117964800);
  int* ridx    = (int*)(ws + 117997568);
  int* ctrl    = (int*)(ws + 118030336);
  int* rank    = (int*)(ws + 118034432);
  int* blkcnt  = (int*)(ws + 118067200);
  int* blkoff  = (int*)(ws + 118068224);

  gate_kernel<<<TOK / 4, 256, 0, stream>>>(x, Wg, bg, assign);
  convert_kernel<<<2048, 256, 0, stream>>>(W1, W1b, NE * FF * DIM);
  convert_kernel<<<2048, 256, 0, stream>>>(W2, W2b, NE * DIM * FF);
  count_rank_kernel<<<NBLK, 256, 0, stream>>>(assign, rank, blkcnt);
  scan2_kernel<<<1, 64, 0, stream>>>(ctrl, blkcnt, blkoff);
  gather_kernel<<<TOK, 256, 0, stream>>>(x, assign, rank, blkoff, ridx, Xb);
  gemm1_kernel<<<8 * NSLOT, 512, 0, stream>>>(Xb, W1b, b1, ctrl, Hb);
  ln_gelu_kernel<<<TOK, 256, 0, stream>>>(Hb, ln_g, ln_b, ctrl + 16);
  gemm2_kernel<<<4 * NSLOT, 512, 0, stream>>>(Hb, W2b, b2, res_scale, ctrl, ridx, x, out);
}